// Round 1
// baseline (60.622 us; speedup 1.0000x reference)
//
#include <hip/hip_runtime.h>
#include <math.h>

#define D_DIM 1024
#define TEMP_INV 14.285714285714286f   // 1/0.07
#define L2EPS 1e-12f

// ws layout (floats):
// [0*N .. 1*N)  nv   = ||v_k||
// [1*N .. 2*N)  na   = ||a_k||
// [2*N .. 3*N)  nt   = ||t_k||
// [3*N .. 4*N)  dva  = v_k . a_k
// [4*N .. 5*N)  dvt  = v_k . t_k
// [5*N .. 6*N)  d0a  = v_0 . a_k
// [6*N .. 7*N)  d0t  = v_0 . t_k

__global__ __launch_bounds__(256) void nce_rowstats(
    const float* __restrict__ v, const float* __restrict__ a,
    const float* __restrict__ t, float* __restrict__ ws, int N)
{
    const int wave = threadIdx.x >> 6;
    const int lane = threadIdx.x & 63;
    const int row  = blockIdx.x * 4 + wave;
    if (row >= N) return;

    const float4* vr = (const float4*)(v + (size_t)row * D_DIM);
    const float4* ar = (const float4*)(a + (size_t)row * D_DIM);
    const float4* tr = (const float4*)(t + (size_t)row * D_DIM);
    const float4* v0 = (const float4*)v;   // row 0 of v, L1/L2 resident

    float sv = 0.f, sa = 0.f, st = 0.f;
    float dva = 0.f, dvt = 0.f, d0a = 0.f, d0t = 0.f;

    #pragma unroll
    for (int it = 0; it < 4; ++it) {
        const int idx = lane + it * 64;        // 256 float4 per row
        const float4 v4 = vr[idx];
        const float4 a4 = ar[idx];
        const float4 t4 = tr[idx];
        const float4 z4 = v0[idx];
        sv  += v4.x*v4.x + v4.y*v4.y + v4.z*v4.z + v4.w*v4.w;
        sa  += a4.x*a4.x + a4.y*a4.y + a4.z*a4.z + a4.w*a4.w;
        st  += t4.x*t4.x + t4.y*t4.y + t4.z*t4.z + t4.w*t4.w;
        dva += v4.x*a4.x + v4.y*a4.y + v4.z*a4.z + v4.w*a4.w;
        dvt += v4.x*t4.x + v4.y*t4.y + v4.z*t4.z + v4.w*t4.w;
        d0a += z4.x*a4.x + z4.y*a4.y + z4.z*a4.z + z4.w*a4.w;
        d0t += z4.x*t4.x + z4.y*t4.y + z4.z*t4.z + z4.w*t4.w;
    }

    // wave (64-lane) butterfly reduce of 7 values
    #pragma unroll
    for (int off = 32; off >= 1; off >>= 1) {
        sv  += __shfl_down(sv,  off);
        sa  += __shfl_down(sa,  off);
        st  += __shfl_down(st,  off);
        dva += __shfl_down(dva, off);
        dvt += __shfl_down(dvt, off);
        d0a += __shfl_down(d0a, off);
        d0t += __shfl_down(d0t, off);
    }

    if (lane == 0) {
        ws[0*N + row] = sqrtf(sv);
        ws[1*N + row] = sqrtf(sa);
        ws[2*N + row] = sqrtf(st);
        ws[3*N + row] = dva;
        ws[4*N + row] = dvt;
        ws[5*N + row] = d0a;
        ws[6*N + row] = d0t;
    }
}

__device__ __forceinline__ float block_reduce_1024(float val, float* sred) {
    // 1024 threads = 16 waves. sred must hold >= 16 floats.
    const int lane = threadIdx.x & 63;
    const int wave = threadIdx.x >> 6;
    __syncthreads();   // protect sred reuse across successive calls
    #pragma unroll
    for (int off = 32; off >= 1; off >>= 1) val += __shfl_down(val, off);
    if (lane == 0) sred[wave] = val;
    __syncthreads();
    float r = 0.f;
    if (wave == 0) {
        r = (lane < 16) ? sred[lane] : 0.f;
        #pragma unroll
        for (int off = 8; off >= 1; off >>= 1) r += __shfl_down(r, off);
        if (lane == 0) sred[0] = r;
    }
    __syncthreads();
    return sred[0];
}

__global__ __launch_bounds__(1024) void nce_finalize(
    const float* __restrict__ v, const float* __restrict__ a,
    const float* __restrict__ t, const float* __restrict__ ws,
    float* __restrict__ out, int N)
{
    __shared__ float sred[16];
    const int tid = threadIdx.x;

    const float* nv  = ws + 0 * (size_t)N;
    const float* na  = ws + 1 * (size_t)N;
    const float* nt  = ws + 2 * (size_t)N;
    const float* dva = ws + 3 * (size_t)N;
    const float* dvt = ws + 4 * (size_t)N;
    const float* d0a = ws + 5 * (size_t)N;
    const float* d0t = ws + 6 * (size_t)N;

    const float nv0 = fmaxf(nv[0], L2EPS);
    const float nv1 = fmaxf(nv[1], L2EPS);
    const float na0 = fmaxf(na[0], L2EPS);
    const float nt0 = fmaxf(nt[0], L2EPS);

    // ---- Phase A: extras ea = v1.a0, et = v1.t0 (D=1024, one elem/thread)
    float pea = v[D_DIM + tid] * a[tid];
    float pet = v[D_DIM + tid] * t[tid];
    const float ea = block_reduce_1024(pea, sred);
    const float et = block_reduce_1024(pet, sred);

    // ---- Phase B: sum_neg over j = 1..N-1 of exp(row0_j) + exp(extra)
    float sna = 0.f, snt = 0.f;
    for (int j = tid; j < N; j += 1024) {
        if (j == 0) continue;
        const float inv_a = 1.0f / (nv0 * fmaxf(na[j], L2EPS));
        const float inv_t = 1.0f / (nv0 * fmaxf(nt[j], L2EPS));
        sna += expf(d0a[j] * inv_a * TEMP_INV);
        snt += expf(d0t[j] * inv_t * TEMP_INV);
    }
    float sum_neg_a = block_reduce_1024(sna, sred);
    float sum_neg_t = block_reduce_1024(snt, sred);
    sum_neg_a += expf(ea / (nv1 * na0) * TEMP_INV);
    sum_neg_t += expf(et / (nv1 * nt0) * TEMP_INV);

    // ---- Phase C: loss sums
    float la = 0.f, lt = 0.f;
    for (int k = tid; k < N; k += 1024) {
        const float nvk = fmaxf(nv[k], L2EPS);
        const float pos_a = dva[k] / (nvk * fmaxf(na[k], L2EPS)) * TEMP_INV;
        const float pos_t = dvt[k] / (nvk * fmaxf(nt[k], L2EPS)) * TEMP_INV;
        float lla = logf(expf(pos_a) + sum_neg_a) - pos_a;
        float llt = logf(expf(pos_t) + sum_neg_t) - pos_t;
        if (isnan(lla)) lla = 0.f;
        if (isnan(llt)) llt = 0.f;
        la += lla;
        lt += llt;
    }
    la = block_reduce_1024(la, sred);
    lt = block_reduce_1024(lt, sred);

    if (tid == 0) {
        out[0] = la / (float)N;
        out[1] = lt / (float)N;
    }
}

extern "C" void kernel_launch(void* const* d_in, const int* in_sizes, int n_in,
                              void* d_out, int out_size, void* d_ws, size_t ws_size,
                              hipStream_t stream) {
    const float* v = (const float*)d_in[0];
    const float* a = (const float*)d_in[1];
    const float* t = (const float*)d_in[2];
    float* out = (float*)d_out;
    float* ws  = (float*)d_ws;
    const int N = in_sizes[0] / D_DIM;   // 16384

    const int blocks = (N + 3) / 4;      // one 64-lane wave per row
    nce_rowstats<<<blocks, 256, 0, stream>>>(v, a, t, ws, N);
    nce_finalize<<<1, 1024, 0, stream>>>(v, a, t, ws, out, N);
}